// Round 10
// baseline (954.204 us; speedup 1.0000x reference)
//
#include <hip/hip_runtime.h>

typedef __attribute__((ext_vector_type(4))) float f32x4;
typedef __attribute__((ext_vector_type(8))) short s16x8;
typedef unsigned int u32;

#define XDIM 440
#define ODIM 220
#define RPB  32          // rows per block
#define TPB  128         // 2 waves; wave w owns rows [w*16, w*16+16)
#define XAW  68          // row stride (floats) for xslF/ActF: %32=4 -> <=2-way banks

// ---------- split helpers ----------
__device__ __forceinline__ u32 cvtpk(float a, float b){
    u32 r; asm("v_cvt_pk_bf16_f32 %0, %1, %2" : "=v"(r) : "v"(a), "v"(b)); return r;
}
// split 8 f32 -> bf16 hi/lo fragments (hi=rne(v), lo=rne(v-hi); v-hi exact)
__device__ __forceinline__ void split8pk(const float* v, s16x8& h, s16x8& l){
    uint4 hu, lu; u32* hp=(u32*)&hu; u32* lp=(u32*)&lu;
    #pragma unroll
    for (int j=0;j<4;++j){
        u32 hk = cvtpk(v[2*j], v[2*j+1]);
        float h0 = __builtin_bit_cast(float, hk<<16);
        float h1 = __builtin_bit_cast(float, hk & 0xFFFF0000u);
        lp[j] = cvtpk(v[2*j]-h0, v[2*j+1]-h1);
        hp[j] = hk;
    }
    h = __builtin_bit_cast(s16x8,hu); l = __builtin_bit_cast(s16x8,lu);
}
// read 8 f32 from LDS, split at read (each elem consumed by exactly one lane)
__device__ __forceinline__ void ldsplit(const float* p, s16x8& h, s16x8& l){
    float a[8];
    *(float4*)(a)   = *(const float4*)(p);
    *(float4*)(a+4) = *(const float4*)(p+4);
    split8pk(a,h,l);
}
__device__ __forceinline__ s16x8 ld8u(const unsigned short* p){ return *(const s16x8*)p; }

// D += A*B, split-bf16: AhBh + AhBl + AlBh (AlBl dropped, ~2^-18)
__device__ __forceinline__ f32x4 mm3(s16x8 ah, s16x8 al, s16x8 bh, s16x8 bl, f32x4 c){
    c = __builtin_amdgcn_mfma_f32_16x16x32_bf16(ah, bh, c, 0, 0, 0);
    c = __builtin_amdgcn_mfma_f32_16x16x32_bf16(ah, bl, c, 0, 0, 0);
    c = __builtin_amdgcn_mfma_f32_16x16x32_bf16(al, bh, c, 0, 0, 0);
    return c;
}

// ---------- weight prep: split to bf16 hi/lo, pad to [240][64] ----------
// rows: [0..47]=bW1 [48..95]=bW2 [96..111]=bW3 [112..159]=sW1 [160..207]=sW2 [208..239]=sW3
__device__ __forceinline__ unsigned short bf_rne(float f){
    unsigned u = __builtin_bit_cast(unsigned, f);
    return (unsigned short)((u + 0x7FFFu + ((u >> 16) & 1u)) >> 16);
}

__global__ void prep_w(const float* __restrict__ bW1, const float* __restrict__ bW2,
                       const float* __restrict__ bW3, const float* __restrict__ sW1,
                       const float* __restrict__ sW2, const float* __restrict__ sW3,
                       const float* __restrict__ bb1, const float* __restrict__ bb2,
                       const float* __restrict__ bb3, const float* __restrict__ sb1,
                       const float* __restrict__ sb2, const float* __restrict__ sb3,
                       unsigned short* __restrict__ WH, unsigned short* __restrict__ WL,
                       float* __restrict__ BIAS)
{
    int i = blockIdx.x * 256 + threadIdx.x;
    if (i < 15360) {
        int n = i >> 6, k = i & 63;
        float w = 0.f;
        if      (n < 48)  { int r = n;     if (r < 40 && k < 40) w = bW1[r*40+k]; }
        else if (n < 96)  { int r = n-48;  if (r < 40 && k < 40) w = bW2[r*40+k]; }
        else if (n < 112) { int r = n-96;  if (r < 10 && k < 40) w = bW3[r*40+k]; }
        else if (n < 160) { int r = n-112; if (r < 41 && k < 41) w = sW1[r*41+k]; }
        else if (n < 208) { int r = n-160; if (r < 41 && k < 41) w = sW2[r*41+k]; }
        else              { int r = n-208; if (r < 22 && k < 41) w = sW3[r*41+k]; }
        unsigned short h = bf_rne(w);
        float hf = __builtin_bit_cast(float, ((unsigned)h) << 16);
        WH[i] = h; WL[i] = bf_rne(w - hf);
    } else if (i < 15600) {
        int n = i - 15360;
        float b;
        if      (n < 48)  b = (n     < 40) ? bb1[n]     : 0.f;
        else if (n < 96)  b = (n-48  < 40) ? bb2[n-48]  : 0.f;
        else if (n < 112) b = (n-96  < 10) ? bb3[n-96]  : -1e30f;
        else if (n < 160) b = (n-112 < 41) ? sb1[n-112] : 0.f;
        else if (n < 208) b = (n-160 < 41) ? sb2[n-160] : 0.f;
        else              b = (n-208 < 22) ? sb3[n-208] : -1e30f;
        BIAS[n] = b;
    }
}

// ---------- slot staging (raw f32, no pre-split) ----------
__device__ __forceinline__ void stage_loadF(const float* __restrict__ x, int R0, int S,
                                            int tid, float4* pf){
    #pragma unroll
    for (int it = 0; it < 3; ++it){
        int f = tid + TPB*it;
        if (f < 320){
            int r = f/10, c4 = f - r*10;
            pf[it] = *(const float4*)(x + (size_t)(R0+r)*XDIM + 40 + S*40 + c4*4);
        }
    }
}
__device__ __forceinline__ void stage_writeF(float (*xb)[XAW], const float* iap, int S,
                                             int tid, const float4* pf){
    #pragma unroll
    for (int it = 0; it < 3; ++it){
        int f = tid + TPB*it;
        if (f < 320){
            int r = f/10, c4 = f - r*10;
            *(float4*)&xb[r][c4*4] = pf[it];
        }
    }
    if (tid < RPB) xb[tid][40] = iap[tid*10 + S];   // iab input (k=40)
}

__global__ __launch_bounds__(TPB, 3) void ran3(
    const float* __restrict__ x,
    const unsigned short* __restrict__ WH,
    const unsigned short* __restrict__ WL,
    const float* __restrict__ BIAS,
    float* __restrict__ wsout,      // mode1: slot-major staging buffer
    float* __restrict__ out,        // mode0: direct scattered output
    int mode)
{
    __shared__ float xslF[RPB][XAW];   // slot inputs, raw f32 (8.5 KB)
    __shared__ float ActF[RPB][XAW];   // activations, raw f32 (8.5 KB)
    __shared__ float ia[RPB][10];      // big-net softmax (1.25 KB)
    __shared__ float obS[2][352];      // per-wave out staging (2.75 KB)
    // total 21.0 KB -> 7 blocks/CU = 14 waves/CU

    const int tid  = threadIdx.x;
    const int l    = tid & 63;
    const int w    = tid >> 6;
    const int q    = l >> 4;
    const int li   = l & 15;
    const int w16  = w * 16;
    const int R0   = blockIdx.x * RPB;
    const int arow = w16 + li;

    // zero pads once: xslF cols 40..67, ActF cols 48..67
    for (int i = tid; i < RPB*28; i += TPB) xslF[i/28][40 + i%28] = 0.f;
    for (int i = tid; i < RPB*20; i += TPB) ActF[i/20][48 + i%20] = 0.f;
    __syncthreads();

    // ================= BIG NET (ActF rows are wave-private) =================
    {   // L1 direct from x
        const float* xp = x + (size_t)(R0 + arow) * XDIM;
        float a0[8], a1[8];
        *(float4*)(a0)   = *(const float4*)(xp + q*8);
        *(float4*)(a0+4) = *(const float4*)(xp + q*8 + 4);
        if (q == 0){
            *(float4*)(a1)   = *(const float4*)(xp + 32);
            *(float4*)(a1+4) = *(const float4*)(xp + 36);
        } else {
            #pragma unroll
            for (int j=0;j<8;++j) a1[j] = 0.f;
        }
        s16x8 ah0,al0,ah1,al1;
        split8pk(a0, ah0, al0); split8pk(a1, ah1, al1);
        #pragma unroll
        for (int nt=0; nt<3; ++nt){
            int n = nt*16 + li; float b = BIAS[n];
            f32x4 acc = {b,b,b,b};
            acc = mm3(ah0,al0, ld8u(WH+n*64+q*8),    ld8u(WL+n*64+q*8),    acc);
            acc = mm3(ah1,al1, ld8u(WH+n*64+32+q*8), ld8u(WL+n*64+32+q*8), acc);
            #pragma unroll
            for (int r=0;r<4;++r)
                ActF[w16+q*4+r][nt*16+li] = fmaxf(acc[r],0.f);
        }
    }
    {   // L2
        s16x8 ah0,al0,ah1,al1;
        ldsplit(&ActF[arow][q*8],    ah0, al0);
        ldsplit(&ActF[arow][32+q*8], ah1, al1);
        #pragma unroll
        for (int nt=0; nt<3; ++nt){
            int n = 48+nt*16+li; float b = BIAS[n];
            f32x4 acc = {b,b,b,b};
            acc = mm3(ah0,al0, ld8u(WH+n*64+q*8),    ld8u(WL+n*64+q*8),    acc);
            acc = mm3(ah1,al1, ld8u(WH+n*64+32+q*8), ld8u(WL+n*64+32+q*8), acc);
            #pragma unroll
            for (int r=0;r<4;++r)
                ActF[w16+q*4+r][nt*16+li] = fmaxf(acc[r],0.f);
        }
    }
    {   // L3 + softmax -> ia
        s16x8 ah0,al0,ah1,al1;
        ldsplit(&ActF[arow][q*8],    ah0, al0);
        ldsplit(&ActF[arow][32+q*8], ah1, al1);
        int n = 96+li; float b = BIAS[n];
        f32x4 acc = {b,b,b,b};
        acc = mm3(ah0,al0, ld8u(WH+n*64+q*8),    ld8u(WL+n*64+q*8),    acc);
        acc = mm3(ah1,al1, ld8u(WH+n*64+32+q*8), ld8u(WL+n*64+32+q*8), acc);
        #pragma unroll
        for (int r=0;r<4;++r){
            float v = acc[r];
            float m = v;
            m = fmaxf(m, __shfl_xor(m,1)); m = fmaxf(m, __shfl_xor(m,2));
            m = fmaxf(m, __shfl_xor(m,4)); m = fmaxf(m, __shfl_xor(m,8));
            float e = __expf(v - m);
            float sum = e;
            sum += __shfl_xor(sum,1); sum += __shfl_xor(sum,2);
            sum += __shfl_xor(sum,4); sum += __shfl_xor(sum,8);
            float p = __fdividef(e, sum);
            if (li < 10) ia[w16+q*4+r][li] = p;
        }
    }
    __syncthreads();   // ia visible

    // stage slot 0
    {
        float4 pf[3];
        stage_loadF(x, R0, 0, tid, pf);
        stage_writeF(xslF, &ia[0][0], 0, tid, pf);
    }
    __syncthreads();

    // ================= SMALL NET: 10 slots =================
    #pragma unroll 1
    for (int s = 0; s < 10; ++s){
        float4 pf[3];
        if (s < 9) stage_loadF(x, R0, s+1, tid, pf);     // early issue

        // ---- L1: xslF -> ActF ----
        {
            s16x8 ah0,al0,ah1,al1;
            ldsplit(&xslF[arow][q*8],    ah0, al0);
            ldsplit(&xslF[arow][32+q*8], ah1, al1);
            #pragma unroll
            for (int nt=0; nt<3; ++nt){
                int n = 112+nt*16+li; float b = BIAS[n];
                f32x4 acc = {b,b,b,b};
                acc = mm3(ah0,al0, ld8u(WH+n*64+q*8),    ld8u(WL+n*64+q*8),    acc);
                acc = mm3(ah1,al1, ld8u(WH+n*64+32+q*8), ld8u(WL+n*64+32+q*8), acc);
                #pragma unroll
                for (int r=0;r<4;++r)
                    ActF[w16+q*4+r][nt*16+li] = fmaxf(acc[r],0.f);
            }
        }
        __syncthreads();                 // all xslF reads complete
        if (s < 9) stage_writeF(xslF, &ia[0][0], s+1, tid, pf);

        // ---- L2: ActF -> ActF ----
        {
            s16x8 ah0,al0,ah1,al1;
            ldsplit(&ActF[arow][q*8],    ah0, al0);
            ldsplit(&ActF[arow][32+q*8], ah1, al1);
            #pragma unroll
            for (int nt=0; nt<3; ++nt){
                int n = 160+nt*16+li; float b = BIAS[n];
                f32x4 acc = {b,b,b,b};
                acc = mm3(ah0,al0, ld8u(WH+n*64+q*8),    ld8u(WL+n*64+q*8),    acc);
                acc = mm3(ah1,al1, ld8u(WH+n*64+32+q*8), ld8u(WL+n*64+32+q*8), acc);
                #pragma unroll
                for (int r=0;r<4;++r)
                    ActF[w16+q*4+r][nt*16+li] = fmaxf(acc[r],0.f);
            }
        }
        // ---- L3 + softmax*iab -> obS -> global ----
        {
            s16x8 ah0,al0,ah1,al1;
            ldsplit(&ActF[arow][q*8],    ah0, al0);
            ldsplit(&ActF[arow][32+q*8], ah1, al1);
            int n6 = 208+li, n7 = 224+li;
            float b6 = BIAS[n6], b7 = BIAS[n7];
            f32x4 a6 = {b6,b6,b6,b6}, a7 = {b7,b7,b7,b7};
            a6 = mm3(ah0,al0, ld8u(WH+n6*64+q*8),    ld8u(WL+n6*64+q*8),    a6);
            a6 = mm3(ah1,al1, ld8u(WH+n6*64+32+q*8), ld8u(WL+n6*64+32+q*8), a6);
            a7 = mm3(ah0,al0, ld8u(WH+n7*64+q*8),    ld8u(WL+n7*64+q*8),    a7);
            a7 = mm3(ah1,al1, ld8u(WH+n7*64+32+q*8), ld8u(WL+n7*64+32+q*8), a7);
            #pragma unroll
            for (int r=0;r<4;++r){
                float v0 = a6[r], v1 = a7[r];
                float m = fmaxf(v0, v1);
                m = fmaxf(m, __shfl_xor(m,1)); m = fmaxf(m, __shfl_xor(m,2));
                m = fmaxf(m, __shfl_xor(m,4)); m = fmaxf(m, __shfl_xor(m,8));
                float e0 = __expf(v0 - m), e1 = __expf(v1 - m);
                float sum = e0 + e1;
                sum += __shfl_xor(sum,1); sum += __shfl_xor(sum,2);
                sum += __shfl_xor(sum,4); sum += __shfl_xor(sum,8);
                int lr = w16 + q*4 + r;
                float sc = __fdividef(ia[lr][s], sum);
                obS[w][(q*4+r)*22 + li] = e0 * sc;
                if (li < 6) obS[w][(q*4+r)*22 + 16 + li] = e1 * sc;
            }
            // flush wave-private obS (same-wave LDS ordering; no barrier needed)
            if (mode){
                // coalesced full-line: ws layout [tile][s][wave][16rows*22]
                float* dst = wsout + (((size_t)blockIdx.x*10 + s)*2 + w)*352;
                #pragma unroll
                for (int it=0; it<2; ++it){
                    int i = l + 64*it;
                    if (i < 88) *(float4*)(dst + 4*i) = *(const float4*)&obS[w][4*i];
                }
            } else {
                #pragma unroll
                for (int it=0; it<6; ++it){
                    int i = l + 64*it;
                    if (i < 352){
                        int lr = i/22, c = i - lr*22;
                        out[(size_t)(R0 + w16 + lr)*ODIM + s*22 + c] = obS[w][i];
                    }
                }
            }
        }
        __syncthreads();   // stage_write visible for next L1
    }
}

// ---------- fixup: slot-major ws -> row-major out, fully coalesced ----------
__global__ __launch_bounds__(256) void fixup(const float* __restrict__ ws2,
                                             float* __restrict__ out)
{
    __shared__ float tb[7040];          // 32 rows x 220 = one tile (28.2 KB)
    const int t = threadIdx.x;
    const size_t tile = blockIdx.x;
    const float4* src = (const float4*)ws2 + tile*1760;
    float4*       dst = (float4*)out + tile*1760;

    #pragma unroll
    for (int it = 0; it < 7; ++it){
        int i = t + 256*it;
        if (i < 1760) *(float4*)&tb[4*i] = src[i];
    }
    __syncthreads();
    #pragma unroll
    for (int it = 0; it < 7; ++it){
        int i = t + 256*it;
        if (i < 1760){
            int o = 4*i;                 // out-flat within tile (row-major)
            int r = o / 220, cc = o - r*220;
            float4 v;
            #pragma unroll
            for (int j = 0; j < 4; ++j){
                int ccj = cc + j;
                int s = ccj / 22, c = ccj - s*22;
                ((float*)&v)[j] = tb[s*704 + r*22 + c];
            }
            dst[i] = v;
        }
    }
}

extern "C" void kernel_launch(void* const* d_in, const int* in_sizes, int n_in,
                              void* d_out, int out_size, void* d_ws, size_t ws_size,
                              hipStream_t stream)
{
    (void)n_in; (void)out_size;
    const float* x   = (const float*)d_in[0];
    const float* bW1 = (const float*)d_in[1];
    const float* bb1 = (const float*)d_in[2];
    const float* bW2 = (const float*)d_in[3];
    const float* bb2 = (const float*)d_in[4];
    const float* bW3 = (const float*)d_in[5];
    const float* bb3 = (const float*)d_in[6];
    const float* sW1 = (const float*)d_in[7];
    const float* sb1 = (const float*)d_in[8];
    const float* sW2 = (const float*)d_in[9];
    const float* sb2 = (const float*)d_in[10];
    const float* sW3 = (const float*)d_in[11];
    const float* sb3 = (const float*)d_in[12];
    float* outp = (float*)d_out;

    unsigned short* WH = (unsigned short*)d_ws;        // 15360 ush
    unsigned short* WL = WH + 15360;                   // 15360 ush
    float* BIAS = (float*)(WH + 30720);                // 240 f
    float* ws2  = (float*)((char*)d_ws + 65536);

    const int rows  = in_sizes[0] / XDIM;              // 262144
    const int tiles = rows / RPB;                      // 8192

    const size_t need = 65536 + (size_t)tiles * RPB * ODIM * 4;  // ~230.8 MB
    const int mode = (ws_size >= need) ? 1 : 0;

    prep_w<<<61, 256, 0, stream>>>(bW1, bW2, bW3, sW1, sW2, sW3,
                                   bb1, bb2, bb3, sb1, sb2, sb3, WH, WL, BIAS);

    ran3<<<tiles, TPB, 0, stream>>>(x, WH, WL, BIAS, ws2, outp, mode);
    if (mode)
        fixup<<<tiles, 256, 0, stream>>>(ws2, outp);
}

// Round 11
// 620.291 us; speedup vs baseline: 1.5383x; 1.5383x over previous
//
#include <hip/hip_runtime.h>

typedef __attribute__((ext_vector_type(4))) float f32x4;
typedef __attribute__((ext_vector_type(8))) short s16x8;
typedef unsigned int u32;
typedef unsigned short ushort;

#define XDIM 440
#define ODIM 220
#define RPB  48          // rows per block (3 waves x 16 rows, wave-private)
#define TPB  192

// ---------- split helpers ----------
__device__ __forceinline__ u32 cvtpk(float a, float b){
    u32 r; asm("v_cvt_pk_bf16_f32 %0, %1, %2" : "=v"(r) : "v"(a), "v"(b)); return r;
}
// split 8 f32 -> bf16 hi/lo fragments (hi=rne(v), lo=rne(v-hi); v-hi exact)
__device__ __forceinline__ void split8pk(const float* v, s16x8& h, s16x8& l){
    uint4 hu, lu; u32* hp=(u32*)&hu; u32* lp=(u32*)&lu;
    #pragma unroll
    for (int j=0;j<4;++j){
        u32 hk = cvtpk(v[2*j], v[2*j+1]);
        float h0 = __builtin_bit_cast(float, hk<<16);
        float h1 = __builtin_bit_cast(float, hk & 0xFFFF0000u);
        lp[j] = cvtpk(v[2*j]-h0, v[2*j+1]-h1);
        hp[j] = hk;
    }
    h = __builtin_bit_cast(s16x8,hu); l = __builtin_bit_cast(s16x8,lu);
}
__device__ __forceinline__ void ldsplit(const float* p, s16x8& h, s16x8& l){
    float a[8];
    *(float4*)(a)   = *(const float4*)(p);
    *(float4*)(a+4) = *(const float4*)(p+4);
    split8pk(a,h,l);
}
__device__ __forceinline__ s16x8 ld8u(const ushort* p){ return *(const s16x8*)p; }

// D += A*B, split-bf16: AhBh + AhBl + AlBh (AlBl dropped, ~2^-18)
__device__ __forceinline__ f32x4 mm3(s16x8 ah, s16x8 al, s16x8 bh, s16x8 bl, f32x4 c){
    c = __builtin_amdgcn_mfma_f32_16x16x32_bf16(ah, bh, c, 0, 0, 0);
    c = __builtin_amdgcn_mfma_f32_16x16x32_bf16(ah, bl, c, 0, 0, 0);
    c = __builtin_amdgcn_mfma_f32_16x16x32_bf16(al, bh, c, 0, 0, 0);
    return c;
}

__device__ __forceinline__ ushort bf_rne(float f){
    unsigned u = __builtin_bit_cast(unsigned, f);
    return (ushort)((u + 0x7FFFu + ((u >> 16) & 1u)) >> 16);
}

// ---------- weight prep ----------
// row-major WH/WL [240][64] (big net uses rows 0..111), BIAS[240],
// WF frag-major: 32 frags (t2 0..7 x ks 0..1 x half 0..1) x [lane 0..63][8 shorts]
//   value = Wsmall[112 + t2*16 + (lane&15)][ks*32 + (lane>>4)*8 + j]
__global__ void prep_w(const float* __restrict__ bW1, const float* __restrict__ bW2,
                       const float* __restrict__ bW3, const float* __restrict__ sW1,
                       const float* __restrict__ sW2, const float* __restrict__ sW3,
                       const float* __restrict__ bb1, const float* __restrict__ bb2,
                       const float* __restrict__ bb3, const float* __restrict__ sb1,
                       const float* __restrict__ sb2, const float* __restrict__ sb3,
                       ushort* __restrict__ WH, ushort* __restrict__ WL,
                       float* __restrict__ BIAS, ushort* __restrict__ WF)
{
    int i = blockIdx.x * 256 + threadIdx.x;
    if (i < 15360) {
        int n = i >> 6, k = i & 63;
        float w = 0.f;
        if      (n < 48)  { int r = n;     if (r < 40 && k < 40) w = bW1[r*40+k]; }
        else if (n < 96)  { int r = n-48;  if (r < 40 && k < 40) w = bW2[r*40+k]; }
        else if (n < 112) { int r = n-96;  if (r < 10 && k < 40) w = bW3[r*40+k]; }
        else if (n < 160) { int r = n-112; if (r < 41 && k < 41) w = sW1[r*41+k]; }
        else if (n < 208) { int r = n-160; if (r < 41 && k < 41) w = sW2[r*41+k]; }
        else              { int r = n-208; if (r < 22 && k < 41) w = sW3[r*41+k]; }
        ushort h = bf_rne(w);
        float hf = __builtin_bit_cast(float, ((unsigned)h) << 16);
        WH[i] = h; WL[i] = bf_rne(w - hf);
    } else if (i < 15600) {
        int n = i - 15360;
        float b;
        if      (n < 48)  b = (n     < 40) ? bb1[n]     : 0.f;
        else if (n < 96)  b = (n-48  < 40) ? bb2[n-48]  : 0.f;
        else if (n < 112) b = (n-96  < 10) ? bb3[n-96]  : -1e30f;
        else if (n < 160) b = (n-112 < 41) ? sb1[n-112] : 0.f;
        else if (n < 208) b = (n-160 < 41) ? sb2[n-160] : 0.f;
        else              b = (n-208 < 22) ? sb3[n-208] : -1e30f;
        BIAS[n] = b;
    } else if (i < 31984) {
        int e = i - 15600;                      // 0..16383
        int fragid = e >> 9, rem = e & 511;
        int lane = rem >> 3, j = rem & 7;
        int t2 = fragid >> 2, ks = (fragid >> 1) & 1, half = fragid & 1;
        int li = lane & 15, q = lane >> 4;
        int r = t2*16 + li;                     // 0..127 (small-net padded row)
        int k = ks*32 + q*8 + j;
        float w = 0.f;
        if      (r < 48) { if (r < 41 && k < 41)            w = sW1[r*41+k]; }
        else if (r < 96) { int rr=r-48; if (rr<41 && k<41)  w = sW2[rr*41+k]; }
        else             { int rr=r-96; if (rr<22 && k<41)  w = sW3[rr*41+k]; }
        ushort h = bf_rne(w);
        ushort v;
        if (half == 0) v = h;
        else { float hf = __builtin_bit_cast(float, ((unsigned)h)<<16); v = bf_rne(w - hf); }
        WF[fragid*512 + lane*8 + j] = v;
    }
}

__global__ __launch_bounds__(TPB, 2) void ran4(
    const float* __restrict__ x,
    const ushort* __restrict__ WH, const ushort* __restrict__ WL,
    const float* __restrict__ BIASg, const ushort* __restrict__ WFg,
    float* __restrict__ out, int nrow)
{
    __shared__ ushort Wlds[16384];        // small-net weights, frag-major (32 KB)
    __shared__ float  xsl[2][RPB][52];    // slot inputs, wave-private rows (19.9 KB)
    __shared__ float  Act[RPB][68];       // activations, wave-private rows (13.1 KB)
    __shared__ float  ia[RPB][10];        // big softmax, wave-private rows (1.9 KB)
    __shared__ float  obS[3][352];        // per-wave out staging (4.2 KB)
    __shared__ float  biasS[240];         // (1 KB)  total ~72.9 KB -> 2 blocks/CU

    const int tid = threadIdx.x;
    const int l   = tid & 63;
    const int w   = tid >> 6;
    const int q   = l >> 4;
    const int li  = l & 15;
    const int w16 = w * 16;
    const int R0  = blockIdx.x * RPB;
    const int arow = w16 + li;
    const int growC = min(R0 + arow, nrow - 1);   // clamped for loads

    // ---- startup: weights+bias -> LDS, zero pads ----
    {
        const u32* src = (const u32*)WFg;
        u32* dst = (u32*)Wlds;
        for (int i = tid; i < 8192; i += TPB) dst[i] = src[i];
    }
    for (int i = tid; i < 240; i += TPB) biasS[i] = BIASg[i];
    for (int i = tid; i < 2*RPB*11; i += TPB){
        int b = i / (RPB*11), k = i % (RPB*11);
        xsl[b][k/11][41 + k%11] = 0.f;            // cols 41..51 zero
    }
    for (int i = tid; i < RPB*20; i += TPB) Act[i/20][48 + i%20] = 0.f;
    __syncthreads();                               // the ONLY barrier

#define WFRAG(t2,ks,hf) (*(const s16x8*)&Wlds[(((t2)*2+(ks))*2+(hf))*512 + l*8])

    // ================= BIG NET (all wave-private) =================
    {   // L1 direct from x
        const float* xp = x + (size_t)growC * XDIM;
        float a0[8], a1[8];
        *(float4*)(a0)   = *(const float4*)(xp + q*8);
        *(float4*)(a0+4) = *(const float4*)(xp + q*8 + 4);
        if (q == 0){
            *(float4*)(a1)   = *(const float4*)(xp + 32);
            *(float4*)(a1+4) = *(const float4*)(xp + 36);
        } else {
            #pragma unroll
            for (int j=0;j<8;++j) a1[j] = 0.f;
        }
        s16x8 ah0,al0,ah1,al1;
        split8pk(a0, ah0, al0); split8pk(a1, ah1, al1);
        #pragma unroll
        for (int nt=0; nt<3; ++nt){
            int n = nt*16 + li; float b = biasS[n];
            f32x4 acc = {b,b,b,b};
            acc = mm3(ah0,al0, ld8u(WH+n*64+q*8),    ld8u(WL+n*64+q*8),    acc);
            acc = mm3(ah1,al1, ld8u(WH+n*64+32+q*8), ld8u(WL+n*64+32+q*8), acc);
            #pragma unroll
            for (int r=0;r<4;++r)
                Act[w16+q*4+r][nt*16+li] = fmaxf(acc[r],0.f);
        }
    }
    {   // L2
        s16x8 ah0,al0,ah1,al1;
        ldsplit(&Act[arow][q*8],    ah0, al0);
        ldsplit(&Act[arow][32+q*8], ah1, al1);
        #pragma unroll
        for (int nt=0; nt<3; ++nt){
            int n = 48+nt*16+li; float b = biasS[n];
            f32x4 acc = {b,b,b,b};
            acc = mm3(ah0,al0, ld8u(WH+n*64+q*8),    ld8u(WL+n*64+q*8),    acc);
            acc = mm3(ah1,al1, ld8u(WH+n*64+32+q*8), ld8u(WL+n*64+32+q*8), acc);
            #pragma unroll
            for (int r=0;r<4;++r)
                Act[w16+q*4+r][nt*16+li] = fmaxf(acc[r],0.f);
        }
    }
    {   // L3 + softmax -> ia
        s16x8 ah0,al0,ah1,al1;
        ldsplit(&Act[arow][q*8],    ah0, al0);
        ldsplit(&Act[arow][32+q*8], ah1, al1);
        int n = 96+li; float b = biasS[n];
        f32x4 acc = {b,b,b,b};
        acc = mm3(ah0,al0, ld8u(WH+n*64+q*8),    ld8u(WL+n*64+q*8),    acc);
        acc = mm3(ah1,al1, ld8u(WH+n*64+32+q*8), ld8u(WL+n*64+32+q*8), acc);
        #pragma unroll
        for (int r=0;r<4;++r){
            float v = acc[r];
            float m = v;
            m = fmaxf(m, __shfl_xor(m,1)); m = fmaxf(m, __shfl_xor(m,2));
            m = fmaxf(m, __shfl_xor(m,4)); m = fmaxf(m, __shfl_xor(m,8));
            float e = __expf(v - m);
            float sum = e;
            sum += __shfl_xor(sum,1); sum += __shfl_xor(sum,2);
            sum += __shfl_xor(sum,4); sum += __shfl_xor(sum,8);
            float p = __fdividef(e, sum);
            if (li < 10) ia[w16+q*4+r][li] = p;
        }
    }

    // ---- wave-private slot staging: 16 rows x 40 floats, coalesced-ish ----
    // (global loads into pf regs, then LDS writes; iab -> col 40)
    auto stage_load = [&](int S, float4* pf){
        #pragma unroll
        for (int it = 0; it < 3; ++it){
            int i = l + 64*it;
            if (i < 160){
                int r = i/10, c4 = i - r*10;
                int gr = min(R0 + w16 + r, nrow - 1);
                pf[it] = *(const float4*)(x + (size_t)gr*XDIM + 40 + S*40 + c4*4);
            }
        }
    };
    auto stage_write = [&](int b, int S, const float4* pf){
        #pragma unroll
        for (int it = 0; it < 3; ++it){
            int i = l + 64*it;
            if (i < 160){
                int r = i/10, c4 = i - r*10;
                *(float4*)&xsl[b][w16+r][c4*4] = pf[it];
            }
        }
        if (l < 16) xsl[b][w16+l][40] = ia[w16+l][S];
    };

    {   // stage slot 0
        float4 pf[3];
        stage_load(0, pf);
        stage_write(0, 0, pf);
    }

    int cur = 0;
    #pragma unroll 1
    for (int s = 0; s < 10; ++s){
        float4 pf[3];
        if (s < 9) stage_load(s+1, pf);          // issue early, hide under compute

        // ---- L1: xsl[cur] -> Act ----
        {
            s16x8 ah0,al0,ah1,al1;
            ldsplit(&xsl[cur][arow][q*8], ah0, al0);
            if (q == 0)      ldsplit(&xsl[cur][arow][32], ah1, al1);
            else if (q == 1) ldsplit(&xsl[cur][arow][40], ah1, al1);  // iab + zeros
            else { uint4 z={0,0,0,0}; ah1=__builtin_bit_cast(s16x8,z); al1=ah1; }
            #pragma unroll
            for (int nt=0; nt<3; ++nt){
                float b = biasS[112+nt*16+li];
                f32x4 acc = {b,b,b,b};
                acc = mm3(ah0,al0, WFRAG(nt,0,0), WFRAG(nt,0,1), acc);
                acc = mm3(ah1,al1, WFRAG(nt,1,0), WFRAG(nt,1,1), acc);
                #pragma unroll
                for (int r=0;r<4;++r)
                    Act[w16+q*4+r][nt*16+li] = fmaxf(acc[r],0.f);
            }
        }
        if (s < 9) stage_write(cur^1, s+1, pf);

        // ---- L2: Act -> Act ----
        {
            s16x8 ah0,al0,ah1,al1;
            ldsplit(&Act[arow][q*8],    ah0, al0);
            ldsplit(&Act[arow][32+q*8], ah1, al1);
            #pragma unroll
            for (int nt=0; nt<3; ++nt){
                float b = biasS[160+nt*16+li];
                f32x4 acc = {b,b,b,b};
                acc = mm3(ah0,al0, WFRAG(3+nt,0,0), WFRAG(3+nt,0,1), acc);
                acc = mm3(ah1,al1, WFRAG(3+nt,1,0), WFRAG(3+nt,1,1), acc);
                #pragma unroll
                for (int r=0;r<4;++r)
                    Act[w16+q*4+r][nt*16+li] = fmaxf(acc[r],0.f);
            }
        }
        // ---- L3 + softmax*iab -> obS -> out ----
        {
            s16x8 ah0,al0,ah1,al1;
            ldsplit(&Act[arow][q*8],    ah0, al0);
            ldsplit(&Act[arow][32+q*8], ah1, al1);
            float b6 = biasS[208+li], b7 = biasS[224+li];
            f32x4 a6 = {b6,b6,b6,b6}, a7 = {b7,b7,b7,b7};
            a6 = mm3(ah0,al0, WFRAG(6,0,0), WFRAG(6,0,1), a6);
            a6 = mm3(ah1,al1, WFRAG(6,1,0), WFRAG(6,1,1), a6);
            a7 = mm3(ah0,al0, WFRAG(7,0,0), WFRAG(7,0,1), a7);
            a7 = mm3(ah1,al1, WFRAG(7,1,0), WFRAG(7,1,1), a7);
            #pragma unroll
            for (int r=0;r<4;++r){
                float v0 = a6[r], v1 = a7[r];
                float m = fmaxf(v0, v1);
                m = fmaxf(m, __shfl_xor(m,1)); m = fmaxf(m, __shfl_xor(m,2));
                m = fmaxf(m, __shfl_xor(m,4)); m = fmaxf(m, __shfl_xor(m,8));
                float e0 = __expf(v0 - m), e1 = __expf(v1 - m);
                float sum = e0 + e1;
                sum += __shfl_xor(sum,1); sum += __shfl_xor(sum,2);
                sum += __shfl_xor(sum,4); sum += __shfl_xor(sum,8);
                int lr = w16 + q*4 + r;
                float sc = __fdividef(ia[lr][s], sum);
                obS[w][(q*4+r)*22 + li] = e0 * sc;
                if (li < 6) obS[w][(q*4+r)*22 + 16 + li] = e1 * sc;
            }
            // wave-private flush: 16 rows x 11 float2 chunks
            #pragma unroll
            for (int it = 0; it < 3; ++it){
                int i = l + 64*it;
                if (i < 176){
                    int lr = i/11, pc = i - lr*11;
                    if (R0 + w16 + lr < nrow)
                        *(float2*)(out + (size_t)(R0+w16+lr)*ODIM + s*22 + pc*2)
                            = *(const float2*)&obS[w][lr*22 + pc*2];
                }
            }
        }
        cur ^= 1;
    }
#undef WFRAG
}

extern "C" void kernel_launch(void* const* d_in, const int* in_sizes, int n_in,
                              void* d_out, int out_size, void* d_ws, size_t ws_size,
                              hipStream_t stream)
{
    (void)n_in; (void)out_size; (void)ws_size;
    const float* x   = (const float*)d_in[0];
    const float* bW1 = (const float*)d_in[1];
    const float* bb1 = (const float*)d_in[2];
    const float* bW2 = (const float*)d_in[3];
    const float* bb2 = (const float*)d_in[4];
    const float* bW3 = (const float*)d_in[5];
    const float* bb3 = (const float*)d_in[6];
    const float* sW1 = (const float*)d_in[7];
    const float* sb1 = (const float*)d_in[8];
    const float* sW2 = (const float*)d_in[9];
    const float* sb2 = (const float*)d_in[10];
    const float* sW3 = (const float*)d_in[11];
    const float* sb3 = (const float*)d_in[12];
    float* outp = (float*)d_out;

    ushort* WH  = (ushort*)d_ws;                        // [240][64]
    ushort* WL  = WH + 15360;                           // [240][64]
    float*  BIAS= (float*)((char*)d_ws + 61440);        // [240]
    ushort* WF  = (ushort*)((char*)d_ws + 62464);       // 32 frags x 512 shorts

    const int rows = in_sizes[0] / XDIM;                // 262144

    prep_w<<<125, 256, 0, stream>>>(bW1, bW2, bW3, sW1, sW2, sW3,
                                    bb1, bb2, bb3, sb1, sb2, sb3,
                                    WH, WL, BIAS, WF);

    const int grid = (rows + RPB - 1) / RPB;            // 5462
    ran4<<<grid, TPB, 0, stream>>>(x, WH, WL, BIAS, WF, outp, rows);
}

// Round 12
// 292.441 us; speedup vs baseline: 3.2629x; 2.1211x over previous
//
#include <hip/hip_runtime.h>

typedef __attribute__((ext_vector_type(4))) float f32x4;
typedef __attribute__((ext_vector_type(8))) short s16x8;
typedef unsigned int u32;
typedef unsigned short ushort;

#define XDIM 440
#define ODIM 220
#define RPB  128         // rows per block (8 waves x 16 rows, wave-private)
#define TPB  512
#define AW   68          // Act row stride (floats)

// ---------- split helpers ----------
__device__ __forceinline__ u32 cvtpk(float a, float b){
    u32 r; asm("v_cvt_pk_bf16_f32 %0, %1, %2" : "=v"(r) : "v"(a), "v"(b)); return r;
}
// split 8 f32 -> bf16 hi/lo fragments (hi=rne(v), lo=rne(v-hi); v-hi exact)
__device__ __forceinline__ void split8pk(const float* v, s16x8& h, s16x8& l){
    uint4 hu, lu; u32* hp=(u32*)&hu; u32* lp=(u32*)&lu;
    #pragma unroll
    for (int j=0;j<4;++j){
        u32 hk = cvtpk(v[2*j], v[2*j+1]);
        float h0 = __builtin_bit_cast(float, hk<<16);
        float h1 = __builtin_bit_cast(float, hk & 0xFFFF0000u);
        lp[j] = cvtpk(v[2*j]-h0, v[2*j+1]-h1);
        hp[j] = hk;
    }
    h = __builtin_bit_cast(s16x8,hu); l = __builtin_bit_cast(s16x8,lu);
}
__device__ __forceinline__ void ldsplit(const float* p, s16x8& h, s16x8& l){
    float a[8];
    *(float4*)(a)   = *(const float4*)(p);
    *(float4*)(a+4) = *(const float4*)(p+4);
    split8pk(a,h,l);
}
__device__ __forceinline__ s16x8 ld8u(const ushort* p){ return *(const s16x8*)p; }

// D += A*B, split-bf16: AhBh + AhBl + AlBh (AlBl dropped, ~2^-18)
__device__ __forceinline__ f32x4 mm3(s16x8 ah, s16x8 al, s16x8 bh, s16x8 bl, f32x4 c){
    c = __builtin_amdgcn_mfma_f32_16x16x32_bf16(ah, bh, c, 0, 0, 0);
    c = __builtin_amdgcn_mfma_f32_16x16x32_bf16(ah, bl, c, 0, 0, 0);
    c = __builtin_amdgcn_mfma_f32_16x16x32_bf16(al, bh, c, 0, 0, 0);
    return c;
}

__device__ __forceinline__ ushort bf_rne(float f){
    unsigned u = __builtin_bit_cast(unsigned, f);
    return (ushort)((u + 0x7FFFu + ((u >> 16) & 1u)) >> 16);
}

// ---------- weight prep ----------
// WH/WL row-major [240][64] (big net rows 0..111), BIAS[240],
// WF frag-major for small net: 32 frags (t2 0..7 x ks 0..1 x half 0..1) x [lane][8]
//   value = Wsmall[112 + t2*16 + (lane&15)][ks*32 + (lane>>4)*8 + j]
__global__ void prep_w(const float* __restrict__ bW1, const float* __restrict__ bW2,
                       const float* __restrict__ bW3, const float* __restrict__ sW1,
                       const float* __restrict__ sW2, const float* __restrict__ sW3,
                       const float* __restrict__ bb1, const float* __restrict__ bb2,
                       const float* __restrict__ bb3, const float* __restrict__ sb1,
                       const float* __restrict__ sb2, const float* __restrict__ sb3,
                       ushort* __restrict__ WH, ushort* __restrict__ WL,
                       float* __restrict__ BIAS, ushort* __restrict__ WF)
{
    int i = blockIdx.x * 256 + threadIdx.x;
    if (i < 15360) {
        int n = i >> 6, k = i & 63;
        float w = 0.f;
        if      (n < 48)  { int r = n;     if (r < 40 && k < 40) w = bW1[r*40+k]; }
        else if (n < 96)  { int r = n-48;  if (r < 40 && k < 40) w = bW2[r*40+k]; }
        else if (n < 112) { int r = n-96;  if (r < 10 && k < 40) w = bW3[r*40+k]; }
        else if (n < 160) { int r = n-112; if (r < 41 && k < 41) w = sW1[r*41+k]; }
        else if (n < 208) { int r = n-160; if (r < 41 && k < 41) w = sW2[r*41+k]; }
        else              { int r = n-208; if (r < 22 && k < 41) w = sW3[r*41+k]; }
        ushort h = bf_rne(w);
        float hf = __builtin_bit_cast(float, ((unsigned)h) << 16);
        WH[i] = h; WL[i] = bf_rne(w - hf);
    } else if (i < 15600) {
        int n = i - 15360;
        float b;
        if      (n < 48)  b = (n     < 40) ? bb1[n]     : 0.f;
        else if (n < 96)  b = (n-48  < 40) ? bb2[n-48]  : 0.f;
        else if (n < 112) b = (n-96  < 10) ? bb3[n-96]  : -1e30f;
        else if (n < 160) b = (n-112 < 41) ? sb1[n-112] : 0.f;
        else if (n < 208) b = (n-160 < 41) ? sb2[n-160] : 0.f;
        else              b = (n-208 < 22) ? sb3[n-208] : -1e30f;
        BIAS[n] = b;
    } else if (i < 31984) {
        int e = i - 15600;                      // 0..16383
        int fragid = e >> 9, rem = e & 511;
        int lane = rem >> 3, j = rem & 7;
        int t2 = fragid >> 2, ks = (fragid >> 1) & 1, half = fragid & 1;
        int li = lane & 15, q = lane >> 4;
        int r = t2*16 + li;
        int k = ks*32 + q*8 + j;
        float w = 0.f;
        if      (r < 48) { if (r < 41 && k < 41)            w = sW1[r*41+k]; }
        else if (r < 96) { int rr=r-48; if (rr<41 && k<41)  w = sW2[rr*41+k]; }
        else             { int rr=r-96; if (rr<22 && k<41)  w = sW3[rr*41+k]; }
        ushort h = bf_rne(w);
        ushort v;
        if (half == 0) v = h;
        else { float hf = __builtin_bit_cast(float, ((unsigned)h)<<16); v = bf_rne(w - hf); }
        WF[fragid*512 + lane*8 + j] = v;
    }
}

__global__ __launch_bounds__(TPB, 4) void ran5(
    const float* __restrict__ x,
    const ushort* __restrict__ WH, const ushort* __restrict__ WL,
    const float* __restrict__ BIASg, const ushort* __restrict__ WFg,
    float* __restrict__ out, int nrow)
{
    __shared__ ushort Wlds[16384];        // small-net weights, frag-major (32 KB)
    __shared__ float  Act[RPB][AW];       // activations / out staging (34.8 KB)
    __shared__ float  ia[RPB][10];        // big softmax (5.1 KB)
    __shared__ float  biasS[240];         // (1 KB)  total 71.9 KB -> 2 blocks/CU

    const int tid = threadIdx.x;
    const int l   = tid & 63;
    const int w   = tid >> 6;
    const int q   = l >> 4;
    const int li  = l & 15;
    const int w16 = w * 16;
    const int R0  = blockIdx.x * RPB;
    const int arow = w16 + li;
    const int growC = min(R0 + arow, nrow - 1);

    // ---- startup: weights+bias -> LDS, zero Act pad cols 48..67 ----
    {
        const u32* src = (const u32*)WFg;
        u32* dst = (u32*)Wlds;
        for (int i = tid; i < 8192; i += TPB) dst[i] = src[i];
    }
    for (int i = tid; i < 240; i += TPB) biasS[i] = BIASg[i];
    for (int i = tid; i < RPB*20; i += TPB) Act[i/20][48 + i%20] = 0.f;
    __syncthreads();                               // the ONLY barrier

#define WFRAG(t2,ks,hf) (*(const s16x8*)&Wlds[(((t2)*2+(ks))*2+(hf))*512 + l*8])

    // ================= BIG NET (all wave-private) =================
    {   // L1 direct from x
        const float* xp = x + (size_t)growC * XDIM;
        float a0[8], a1[8];
        *(float4*)(a0)   = *(const float4*)(xp + q*8);
        *(float4*)(a0+4) = *(const float4*)(xp + q*8 + 4);
        if (q == 0){
            *(float4*)(a1)   = *(const float4*)(xp + 32);
            *(float4*)(a1+4) = *(const float4*)(xp + 36);
        } else {
            #pragma unroll
            for (int j=0;j<8;++j) a1[j] = 0.f;
        }
        s16x8 ah0,al0,ah1,al1;
        split8pk(a0, ah0, al0); split8pk(a1, ah1, al1);
        #pragma unroll
        for (int nt=0; nt<3; ++nt){
            int n = nt*16 + li; float b = biasS[n];
            f32x4 acc = {b,b,b,b};
            acc = mm3(ah0,al0, ld8u(WH+n*64+q*8),    ld8u(WL+n*64+q*8),    acc);
            acc = mm3(ah1,al1, ld8u(WH+n*64+32+q*8), ld8u(WL+n*64+32+q*8), acc);
            #pragma unroll
            for (int r=0;r<4;++r)
                Act[w16+q*4+r][nt*16+li] = fmaxf(acc[r],0.f);
        }
    }
    {   // L2
        s16x8 ah0,al0,ah1,al1;
        ldsplit(&Act[arow][q*8],    ah0, al0);
        ldsplit(&Act[arow][32+q*8], ah1, al1);
        #pragma unroll
        for (int nt=0; nt<3; ++nt){
            int n = 48+nt*16+li; float b = biasS[n];
            f32x4 acc = {b,b,b,b};
            acc = mm3(ah0,al0, ld8u(WH+n*64+q*8),    ld8u(WL+n*64+q*8),    acc);
            acc = mm3(ah1,al1, ld8u(WH+n*64+32+q*8), ld8u(WL+n*64+32+q*8), acc);
            #pragma unroll
            for (int r=0;r<4;++r)
                Act[w16+q*4+r][nt*16+li] = fmaxf(acc[r],0.f);
        }
    }
    {   // L3 + softmax -> ia
        s16x8 ah0,al0,ah1,al1;
        ldsplit(&Act[arow][q*8],    ah0, al0);
        ldsplit(&Act[arow][32+q*8], ah1, al1);
        int n = 96+li; float b = biasS[n];
        f32x4 acc = {b,b,b,b};
        acc = mm3(ah0,al0, ld8u(WH+n*64+q*8),    ld8u(WL+n*64+q*8),    acc);
        acc = mm3(ah1,al1, ld8u(WH+n*64+32+q*8), ld8u(WL+n*64+32+q*8), acc);
        #pragma unroll
        for (int r=0;r<4;++r){
            float v = acc[r];
            float m = v;
            m = fmaxf(m, __shfl_xor(m,1)); m = fmaxf(m, __shfl_xor(m,2));
            m = fmaxf(m, __shfl_xor(m,4)); m = fmaxf(m, __shfl_xor(m,8));
            float e = __expf(v - m);
            float sum = e;
            sum += __shfl_xor(sum,1); sum += __shfl_xor(sum,2);
            sum += __shfl_xor(sum,4); sum += __shfl_xor(sum,8);
            float p = __fdividef(e, sum);
            if (li < 10) ia[w16+q*4+r][li] = p;
        }
    }

    // ---- per-lane x prefetch (slot inputs live in registers, no LDS) ----
    const float* xrow = x + (size_t)growC * XDIM + 40;
    auto stage_load = [&](int S, float* pf0, float* pf1){
        const float* xp = xrow + S*40;
        *(float4*)(pf0)   = *(const float4*)(xp + q*8);
        *(float4*)(pf0+4) = *(const float4*)(xp + q*8 + 4);
        if (q == 0){
            *(float4*)(pf1)   = *(const float4*)(xp + 32);
            *(float4*)(pf1+4) = *(const float4*)(xp + 36);
        }
    };

    auto compute_slot = [&](int s, const float* pf0, const float* pf1){
        s16x8 ah0,al0,ah1,al1;
        // L1: fragments from registers + iab
        split8pk(pf0, ah0, al0);
        float a1v[8];
        #pragma unroll
        for (int j=0;j<8;++j) a1v[j] = (q==0) ? pf1[j] : 0.f;
        if (q == 1) a1v[0] = ia[arow][s];            // k=40 = iab
        split8pk(a1v, ah1, al1);
        #pragma unroll
        for (int nt=0; nt<3; ++nt){
            float b = biasS[112+nt*16+li];
            f32x4 acc = {b,b,b,b};
            acc = mm3(ah0,al0, WFRAG(nt,0,0), WFRAG(nt,0,1), acc);
            acc = mm3(ah1,al1, WFRAG(nt,1,0), WFRAG(nt,1,1), acc);
            #pragma unroll
            for (int r=0;r<4;++r)
                Act[w16+q*4+r][nt*16+li] = fmaxf(acc[r],0.f);
        }
        // L2
        ldsplit(&Act[arow][q*8],    ah0, al0);
        ldsplit(&Act[arow][32+q*8], ah1, al1);
        #pragma unroll
        for (int nt=0; nt<3; ++nt){
            float b = biasS[160+nt*16+li];
            f32x4 acc = {b,b,b,b};
            acc = mm3(ah0,al0, WFRAG(3+nt,0,0), WFRAG(3+nt,0,1), acc);
            acc = mm3(ah1,al1, WFRAG(3+nt,1,0), WFRAG(3+nt,1,1), acc);
            #pragma unroll
            for (int r=0;r<4;++r)
                Act[w16+q*4+r][nt*16+li] = fmaxf(acc[r],0.f);
        }
        // L3 + softmax*iab -> stage in Act cols 0..21 -> out
        ldsplit(&Act[arow][q*8],    ah0, al0);
        ldsplit(&Act[arow][32+q*8], ah1, al1);
        float b6 = biasS[208+li], b7 = biasS[224+li];
        f32x4 a6 = {b6,b6,b6,b6}, a7 = {b7,b7,b7,b7};
        a6 = mm3(ah0,al0, WFRAG(6,0,0), WFRAG(6,0,1), a6);
        a6 = mm3(ah1,al1, WFRAG(6,1,0), WFRAG(6,1,1), a6);
        a7 = mm3(ah0,al0, WFRAG(7,0,0), WFRAG(7,0,1), a7);
        a7 = mm3(ah1,al1, WFRAG(7,1,0), WFRAG(7,1,1), a7);
        #pragma unroll
        for (int r=0;r<4;++r){
            float v0 = a6[r], v1 = a7[r];
            float m = fmaxf(v0, v1);
            m = fmaxf(m, __shfl_xor(m,1)); m = fmaxf(m, __shfl_xor(m,2));
            m = fmaxf(m, __shfl_xor(m,4)); m = fmaxf(m, __shfl_xor(m,8));
            float e0 = __expf(v0 - m), e1 = __expf(v1 - m);
            float sum = e0 + e1;
            sum += __shfl_xor(sum,1); sum += __shfl_xor(sum,2);
            sum += __shfl_xor(sum,4); sum += __shfl_xor(sum,8);
            int lr = w16 + q*4 + r;
            float sc = __fdividef(ia[lr][s], sum);
            Act[lr][li] = e0 * sc;                   // Act rows are dead here
            if (li < 6) Act[lr][16 + li] = e1 * sc;
        }
        // wave-private flush: 16 rows x 11 float2 chunks
        #pragma unroll
        for (int it = 0; it < 3; ++it){
            int i = l + 64*it;
            if (i < 176){
                int lr = i/11, pc = i - lr*11;
                if (R0 + w16 + lr < nrow)
                    *(float2*)(out + (size_t)(R0+w16+lr)*ODIM + s*22 + pc*2)
                        = *(const float2*)&Act[w16+lr][pc*2];
            }
        }
    };

    float pfA0[8], pfA1[8], pfB0[8], pfB1[8];
    stage_load(0, pfA0, pfA1);
    #pragma unroll 1
    for (int s = 0; s < 10; s += 2){
        stage_load(s+1, pfB0, pfB1);                 // issue early (T14)
        compute_slot(s, pfA0, pfA1);
        if (s+2 < 10) stage_load(s+2, pfA0, pfA1);
        compute_slot(s+1, pfB0, pfB1);
    }
#undef WFRAG
}

extern "C" void kernel_launch(void* const* d_in, const int* in_sizes, int n_in,
                              void* d_out, int out_size, void* d_ws, size_t ws_size,
                              hipStream_t stream)
{
    (void)n_in; (void)out_size; (void)ws_size;
    const float* x   = (const float*)d_in[0];
    const float* bW1 = (const float*)d_in[1];
    const float* bb1 = (const float*)d_in[2];
    const float* bW2 = (const float*)d_in[3];
    const float* bb2 = (const float*)d_in[4];
    const float* bW3 = (const float*)d_in[5];
    const float* bb3 = (const float*)d_in[6];
    const float* sW1 = (const float*)d_in[7];
    const float* sb1 = (const float*)d_in[8];
    const float* sW2 = (const float*)d_in[9];
    const float* sb2 = (const float*)d_in[10];
    const float* sW3 = (const float*)d_in[11];
    const float* sb3 = (const float*)d_in[12];
    float* outp = (float*)d_out;

    ushort* WH  = (ushort*)d_ws;                        // [240][64]
    ushort* WL  = WH + 15360;                           // [240][64]
    float*  BIAS= (float*)((char*)d_ws + 61440);        // [240]
    ushort* WF  = (ushort*)((char*)d_ws + 62464);       // 32 frags x 512 shorts

    const int rows = in_sizes[0] / XDIM;                // 262144

    prep_w<<<125, 256, 0, stream>>>(bW1, bW2, bW3, sW1, sW2, sW3,
                                    bb1, bb2, bb3, sb1, sb2, sb3,
                                    WH, WL, BIAS, WF);

    const int grid = (rows + RPB - 1) / RPB;            // 2048
    ran5<<<grid, TPB, 0, stream>>>(x, WH, WL, BIAS, WF, outp, rows);
}